// Round 1
// baseline (436.768 us; speedup 1.0000x reference)
//
#include <hip/hip_runtime.h>
#include <math.h>

#define B_ 16
#define N_ 4096
#define C_ 128

// ---------------- generic GEMM: out[r][co] = sum_k A[r][k]*W[co][k] (+bias) ----
// tile: 64 rows x 128 cols, K=128. block 256.
__global__ __launch_bounds__(256) void gemm128(const float* __restrict__ A,
    const float* __restrict__ W, const float* __restrict__ bias,
    float* __restrict__ out) {
  __shared__ float a_s[32][64];
  __shared__ float w_s[32][129];
  const int t = threadIdx.x;
  const int r0 = blockIdx.x * 64;
  const int col = t & 127, rg = t >> 7;
  const int srow = t >> 2, skk = (t & 3) * 8;
  const int wk = t & 31, wcg = t >> 5;
  float acc[32];
#pragma unroll
  for (int i = 0; i < 32; i++) acc[i] = 0.f;
  for (int kc = 0; kc < 4; ++kc) {
    __syncthreads();
#pragma unroll
    for (int j = 0; j < 8; j++)
      a_s[skk + j][srow] = A[(size_t)(r0 + srow) * 128 + kc * 32 + skk + j];
#pragma unroll
    for (int j = 0; j < 16; j++) {
      int c2 = wcg * 16 + j;
      w_s[wk][c2] = W[(size_t)c2 * 128 + kc * 32 + wk];
    }
    __syncthreads();
#pragma unroll
    for (int k = 0; k < 32; k++) {
      float wv = w_s[k][col];
      const float4* ar = reinterpret_cast<const float4*>(&a_s[k][rg * 32]);
#pragma unroll
      for (int i = 0; i < 8; i++) {
        float4 a4 = ar[i];
        acc[4 * i + 0] += a4.x * wv;
        acc[4 * i + 1] += a4.y * wv;
        acc[4 * i + 2] += a4.z * wv;
        acc[4 * i + 3] += a4.w * wv;
      }
    }
  }
  float bv = bias ? bias[col] : 0.f;
#pragma unroll
  for (int r = 0; r < 32; r++)
    out[(size_t)(r0 + rg * 32 + r) * 128 + col] = acc[r] + bv;
}

// ------------- patchify conv as gathered GEMM with K-split partials ----------
// rows = B*M (patch rows), K = 128*SR*SR, cols = 128.
// part[ksplit][row][col] partial sums (deterministic; reduced in ln_gelu).
template <int SRV>
__global__ __launch_bounds__(256) void convgemm(const float* __restrict__ x,
    const float* __restrict__ W, float* __restrict__ part, int kchunk) {
  constexpr int WP = 64 / SRV;
  constexpr int M = WP * WP;
  constexpr int ROWS = B_ * M;
  constexpr int KTOT = 128 * SRV * SRV;
  constexpr int LM = (SRV == 8) ? 6 : 8;
  constexpr int LWP = (SRV == 8) ? 3 : 4;
  constexpr int LSS = (SRV == 8) ? 6 : 4;
  constexpr int LSR = (SRV == 8) ? 3 : 2;
  __shared__ float a_s[32][64];
  __shared__ float w_s[32][129];
  const int t = threadIdx.x;
  const int r0 = blockIdx.x * 64;
  const int kb0 = blockIdx.y * kchunk;
  const int col = t & 127, rg = t >> 7;
  const int srow = t >> 2, skk = (t & 3) * 8;
  const int wk = t & 31, wcg = t >> 5;
  const int rglob = r0 + srow;
  const int bb = rglob >> LM;
  const int pm = rglob & (M - 1);
  const int ph = pm >> LWP, pw = pm & (WP - 1);
  float acc[32];
#pragma unroll
  for (int i = 0; i < 32; i++) acc[i] = 0.f;
  const int nkc = kchunk >> 5;
  for (int kc = 0; kc < nkc; ++kc) {
    __syncthreads();
#pragma unroll
    for (int j = 0; j < 8; j++) {
      int k = kb0 + kc * 32 + skk + j;
      int ci = k >> LSS;
      int rem = k & ((1 << LSS) - 1);
      int kh = rem >> LSR, kw = rem & (SRV - 1);
      int pix = (ph * SRV + kh) * 64 + pw * SRV + kw;
      a_s[skk + j][srow] = x[((size_t)(bb * 4096 + pix)) * 128 + ci];
    }
#pragma unroll
    for (int j = 0; j < 16; j++) {
      int c2 = wcg * 16 + j;
      w_s[wk][c2] = W[(size_t)c2 * KTOT + kb0 + kc * 32 + wk];
    }
    __syncthreads();
#pragma unroll
    for (int k = 0; k < 32; k++) {
      float wv = w_s[k][col];
      const float4* ar = reinterpret_cast<const float4*>(&a_s[k][rg * 32]);
#pragma unroll
      for (int i = 0; i < 8; i++) {
        float4 a4 = ar[i];
        acc[4 * i + 0] += a4.x * wv;
        acc[4 * i + 1] += a4.y * wv;
        acc[4 * i + 2] += a4.z * wv;
        acc[4 * i + 3] += a4.w * wv;
      }
    }
  }
#pragma unroll
  for (int r = 0; r < 32; r++)
    part[((size_t)blockIdx.y * ROWS + r0 + rg * 32 + r) * 128 + col] = acc[r];
}

// ---- reduce K-split partials + conv bias, then LayerNorm(c=128) + exact GELU
__global__ __launch_bounds__(128) void ln_gelu(const float* __restrict__ part,
    int nsplit, int rows, const float* __restrict__ cb,
    const float* __restrict__ g, const float* __restrict__ be,
    float* __restrict__ out) {
  const int row = blockIdx.x;
  const int t = threadIdx.x;
  float v = cb[t];
  for (int s = 0; s < nsplit; s++)
    v += part[((size_t)s * rows + row) * 128 + t];
  float sv = v, sq = v * v;
#pragma unroll
  for (int off = 32; off > 0; off >>= 1) {
    sv += __shfl_down(sv, off, 64);
    sq += __shfl_down(sq, off, 64);
  }
  __shared__ float red0[2], red1[2];
  if ((t & 63) == 0) {
    red0[t >> 6] = sv;
    red1[t >> 6] = sq;
  }
  __syncthreads();
  float mean = (red0[0] + red0[1]) * (1.f / 128.f);
  float var = (red1[0] + red1[1]) * (1.f / 128.f) - mean * mean;
  float y = (v - mean) * rsqrtf(var + 1e-5f) * g[t] + be[t];
  out[(size_t)row * 128 + t] = y * 0.5f * (1.f + erff(y * 0.70710678118f));
}

// --------- depthwise 3x3 (pad 1) on v over reduced grid; v' = v + conv ------
// kv layout (b, m, 128); v channels are 64..127. vp layout (b, m, 64).
template <int WP>
__global__ __launch_bounds__(256) void dwconv(const float* __restrict__ kv,
    const float* __restrict__ lw, const float* __restrict__ lb,
    float* __restrict__ vp) {
  constexpr int M = WP * WP;
  constexpr int LM = (WP == 8) ? 6 : 8;
  constexpr int LWPc = (WP == 8) ? 3 : 4;
  int idx = blockIdx.x * 256 + threadIdx.x;
  int ch = idx & 63;
  int rest = idx >> 6;
  int m = rest & (M - 1);
  int bb = rest >> LM;
  int y = m >> LWPc, x0 = m & (WP - 1);
  float s = lb[ch];
#pragma unroll
  for (int ky = 0; ky < 3; ky++) {
    int yy = y + ky - 1;
    if (yy < 0 || yy >= WP) continue;
#pragma unroll
    for (int kx = 0; kx < 3; kx++) {
      int xx = x0 + kx - 1;
      if (xx < 0 || xx >= WP) continue;
      s += kv[((size_t)(bb * M + yy * WP + xx)) * 128 + 64 + ch] *
           lw[ch * 9 + ky * 3 + kx];
    }
  }
  vp[idx] = kv[((size_t)(bb * M + m)) * 128 + 64 + ch] + s;
}

// ------------- fused attention: per-thread row, k/v staged in LDS -----------
// q (b,n,128); k = kv[...,h*32+d]; v = vp[...,h*32+d]; out -> xcat col QOFF+h*32+d
template <int M, int QOFF>
__global__ __launch_bounds__(256) void attn(const float* __restrict__ q,
    const float* __restrict__ kv, const float* __restrict__ vp,
    float* __restrict__ xcat) {
  __shared__ float k_s[M][32];
  __shared__ float v_s[M][32];
  const int t = threadIdx.x;
  const int h = blockIdx.y, b = blockIdx.z;
  const size_t bm = (size_t)b * M;
  for (int e = t; e < M * 32; e += 256) {
    int m = e >> 5, d = e & 31;
    k_s[m][d] = kv[(bm + m) * 128 + h * 32 + d];
    v_s[m][d] = vp[(bm + m) * 64 + h * 32 + d];
  }
  __syncthreads();
  const int n = blockIdx.x * 256 + t;
  const float4* qv =
      reinterpret_cast<const float4*>(&q[((size_t)b * N_ + n) * 128 + QOFF + h * 32]);
  float4 q4[8];
#pragma unroll
  for (int i = 0; i < 8; i++) q4[i] = qv[i];
  float l = 0.f;
  float acc[32];
#pragma unroll
  for (int i = 0; i < 32; i++) acc[i] = 0.f;
  const float scale = 0.17677669529663687f;  // 1/sqrt(32)
  for (int m = 0; m < M; m++) {
    const float4* kr = reinterpret_cast<const float4*>(&k_s[m][0]);
    float s = 0.f;
#pragma unroll
    for (int i = 0; i < 8; i++) {
      float4 k4 = kr[i];
      s += q4[i].x * k4.x + q4[i].y * k4.y + q4[i].z * k4.z + q4[i].w * k4.w;
    }
    // scores are tiny (|s|<~0.3): plain exp-sum softmax, no max tracking
    float p = __expf(s * scale);
    l += p;
    const float4* vr = reinterpret_cast<const float4*>(&v_s[m][0]);
#pragma unroll
    for (int i = 0; i < 8; i++) {
      float4 v4 = vr[i];
      acc[4 * i + 0] += p * v4.x;
      acc[4 * i + 1] += p * v4.y;
      acc[4 * i + 2] += p * v4.z;
      acc[4 * i + 3] += p * v4.w;
    }
  }
  float inv = 1.f / l;
  float4* orow =
      reinterpret_cast<float4*>(&xcat[((size_t)b * N_ + n) * 128 + QOFF + h * 32]);
#pragma unroll
  for (int i = 0; i < 8; i++) {
    float4 o;
    o.x = acc[4 * i + 0] * inv;
    o.y = acc[4 * i + 1] * inv;
    o.z = acc[4 * i + 2] * inv;
    o.w = acc[4 * i + 3] * inv;
    orow[i] = o;
  }
}

extern "C" void kernel_launch(void* const* d_in, const int* in_sizes, int n_in,
                              void* d_out, int out_size, void* d_ws,
                              size_t ws_size, hipStream_t stream) {
  (void)in_sizes; (void)n_in; (void)out_size; (void)ws_size;
  const float* x      = (const float*)d_in[0];
  const float* q_w    = (const float*)d_in[1];
  const float* sr1_w  = (const float*)d_in[2];
  const float* sr1_b  = (const float*)d_in[3];
  const float* n1_g   = (const float*)d_in[4];
  const float* n1_b   = (const float*)d_in[5];
  const float* sr2_w  = (const float*)d_in[6];
  const float* sr2_b  = (const float*)d_in[7];
  const float* n2_g   = (const float*)d_in[8];
  const float* n2_b   = (const float*)d_in[9];
  const float* kv1_w  = (const float*)d_in[10];
  const float* kv2_w  = (const float*)d_in[11];
  const float* lc1_w  = (const float*)d_in[12];
  const float* lc1_b  = (const float*)d_in[13];
  const float* lc2_w  = (const float*)d_in[14];
  const float* lc2_b  = (const float*)d_in[15];
  const float* proj_w = (const float*)d_in[16];
  const float* proj_b = (const float*)d_in[17];

  float* ws   = (float*)d_ws;
  float* qbuf = ws;                 // 8388608
  float* xcat = qbuf + 8388608;     // 8388608
  float* t1   = xcat + 8388608;     // 131072
  float* t2   = t1 + 131072;        // 524288
  float* kv1  = t2 + 524288;        // 131072
  float* kv2  = kv1 + 131072;       // 524288
  float* v1p  = kv2 + 524288;       // 65536
  float* v2p  = v1p + 65536;        // 262144
  // conv partials alias xcat (consumed by ln_gelu before attn writes xcat)
  float* part1 = xcat;              // 16 * 131072
  float* part2 = xcat + 2097152;    // 8  * 524288

  // q = x @ q_w^T
  gemm128<<<1024, 256, 0, stream>>>(x, q_w, nullptr, qbuf);
  // patchify convs (as gathered GEMMs, K-split partials)
  convgemm<8><<<dim3(16, 16), 256, 0, stream>>>(x, sr1_w, part1, 512);
  convgemm<4><<<dim3(64, 8), 256, 0, stream>>>(x, sr2_w, part2, 256);
  // bias + LN + GELU
  ln_gelu<<<1024, 128, 0, stream>>>(part1, 16, 1024, sr1_b, n1_g, n1_b, t1);
  ln_gelu<<<4096, 128, 0, stream>>>(part2, 8, 4096, sr2_b, n2_g, n2_b, t2);
  // kv projections
  gemm128<<<16, 256, 0, stream>>>(t1, kv1_w, nullptr, kv1);
  gemm128<<<64, 256, 0, stream>>>(t2, kv2_w, nullptr, kv2);
  // local depthwise conv on v
  dwconv<8><<<256, 256, 0, stream>>>(kv1, lc1_w, lc1_b, v1p);
  dwconv<16><<<1024, 256, 0, stream>>>(kv2, lc2_w, lc2_b, v2p);
  // fused attention, writes concat buffer
  attn<64, 0><<<dim3(16, 2, 16), 256, 0, stream>>>(qbuf, kv1, v1p, xcat);
  attn<256, 64><<<dim3(16, 2, 16), 256, 0, stream>>>(qbuf, kv2, v2p, xcat);
  // output projection
  gemm128<<<1024, 256, 0, stream>>>(xcat, proj_w, proj_b, (float*)d_out);
}